// Round 10
// baseline (479.514 us; speedup 1.0000x reference)
//
#include <hip/hip_runtime.h>
#include <math.h>

// NoisyTopKRouter: out0 = softmax over top-2 of (x @ route_w^T + route_b) scattered
// into [16384,64]; out1 = top-2 indices (as floats). noise inputs are dead.
//
// R10: lane = TOKEN decomposition (R4-R9 were lane = expert and died on the
// shared LDS pipe: broadcast ds_read_b128 cost ~82us/CU).
//  - acc[64] expert logits per lane; 64 tokens per block (= lanes).
//  - x: reg-staged coalesced (64B/token) -> wave-private 4KB LDS buffer ->
//    ONE ds_read_b128 per 4-k chunk delivers 64 distinct tokens (all useful).
//  - w: wave-uniform addresses -> compiler emits s_load (scalar path, L2-hot,
//    zero vector-memory traffic); FMA reads SGPR + VGPR.
//  - 16-way K-split, log-tree LDS reduction, in-register top-2 on wave 0.
//  - no barriers / manual waitcnt in the K-loop (single wave-private buffer;
//    read-then-write program order; compiler-managed counters).

#define TOKENS 16384
#define EMB    4096
#define NE     64
#define TB     64                 // tokens per block = lanes per wave
#define NWAVES 16
#define KQ     (EMB / NWAVES)     // 256 k per wave (split-K)
#define SCK    16                 // k per staged superchunk (64B per token)
#define NSC    (KQ / SCK)         // 16

// wts[c][e][kk]: c = k>>2 (0..1023), e (0..63), kk = k&3  (1 MB in d_ws)
// -> per 4-k chunk c, the 64 experts' w are 64 contiguous float4s (s_load-able)
__global__ __launch_bounds__(256) void wts_prep_kernel(const float* __restrict__ w,
                                                       float* __restrict__ wts) {
    int idx = blockIdx.x * 256 + threadIdx.x;   // 0 .. 262143, coalesced writes
    int c  = idx >> 8;
    int e  = (idx >> 2) & 63;
    int kk = idx & 3;
    wts[idx] = w[e * EMB + c * 4 + kk];
}

__global__ __launch_bounds__(1024, 1) void router_kernel(const float* __restrict__ x,
                                                         const float* __restrict__ wts,
                                                         const float* __restrict__ rb,
                                                         float* __restrict__ out) {
    // 64 KB. K-loop: per-wave 4KB staging buf at smem + wq*1024 (floats).
    // Reduction: 4 regions of [16][64] float4 (16 KB) at smem + r*4096.
    // Epilogue: p1/p2/i1/i2 arrays at smem[0..255].
    __shared__ __align__(16) float smem[16384];

    const int tid  = threadIdx.x;
    const int lane = tid & 63;                                  // = token
    const int wq   = __builtin_amdgcn_readfirstlane(tid >> 6);
    const long tok0 = (long)blockIdx.x * TB;

    // staging coords: lane l loads, for piece p, token p*16 + (l>>2),
    // 16B k-slot (l&3) -> 64B-aligned contiguous segments per token.
    const int st_t = lane >> 2;
    const int st_s = lane & 3;
    const float* xbase = x + (tok0 + st_t) * (long)EMB + wq * KQ + st_s * 4;

    float* buf = smem + wq * 1024;    // 4 KB wave-private
    // LDS buf layout: chunk-slot s (0..3) at s*256 floats, token t at +t*4.
    // write: lane-distinct, 8 rows (optimal); read: 64 lanes contiguous 1KB.

    const float4* wbase = (const float4*)wts + (long)(wq * (KQ / 4)) * NE;

    float acc[NE];
#pragma unroll
    for (int e = 0; e < NE; ++e) acc[e] = 0.f;

    // prologue: stage superchunk 0
#pragma unroll
    for (int p = 0; p < 4; ++p) {
        const float4 v = *reinterpret_cast<const float4*>(xbase + (long)p * 16 * EMB);
        *reinterpret_cast<float4*>(buf + st_s * 256 + (p * 16 + st_t) * 4) = v;
    }

    for (int sc = 0; sc < NSC; ++sc) {
        // issue next superchunk's global loads early (latency hides under FMAs)
        float4 stg[4];
        if (sc + 1 < NSC) {
#pragma unroll
            for (int p = 0; p < 4; ++p)
                stg[p] = *reinterpret_cast<const float4*>(
                    xbase + (long)p * 16 * EMB + (sc + 1) * SCK);
        }
        // read this superchunk's 4 chunks: lane reads ITS token's 16B each
        float4 xv[4];
#pragma unroll
        for (int c = 0; c < 4; ++c)
            xv[c] = *reinterpret_cast<const float4*>(buf + c * 256 + lane * 4);
        // 1024 FMAs: w via wave-uniform (scalar) loads
#pragma unroll
        for (int c = 0; c < 4; ++c) {
            const float4* __restrict__ wc = wbase + (sc * 4 + c) * NE;
#pragma unroll
            for (int e = 0; e < NE; ++e) {
                const float4 wv = wc[e];
                acc[e] = fmaf(xv[c].w, wv.w, fmaf(xv[c].z, wv.z,
                         fmaf(xv[c].y, wv.y, fmaf(xv[c].x, wv.x, acc[e]))));
            }
        }
        // write-late: staged regs -> LDS for next iteration (wave-private)
        if (sc + 1 < NSC) {
#pragma unroll
            for (int p = 0; p < 4; ++p)
                *reinterpret_cast<float4*>(buf + st_s * 256 + (p * 16 + st_t) * 4) = stg[p];
        }
    }

    // ---- log-tree cross-wave reduction; regions r: [j 0..15][t 0..63] float4
    auto red_write = [&](int r) {
#pragma unroll
        for (int j = 0; j < 16; ++j)
            *reinterpret_cast<float4*>(smem + r * 4096 + (j * 64 + lane) * 4) =
                make_float4(acc[4 * j], acc[4 * j + 1], acc[4 * j + 2], acc[4 * j + 3]);
    };
    auto red_add = [&](int r) {
#pragma unroll
        for (int j = 0; j < 16; ++j) {
            const float4 v = *reinterpret_cast<const float4*>(
                smem + r * 4096 + (j * 64 + lane) * 4);
            acc[4 * j] += v.x; acc[4 * j + 1] += v.y;
            acc[4 * j + 2] += v.z; acc[4 * j + 3] += v.w;
        }
    };

    __syncthreads();
    if (wq >= 8 && wq < 12) red_write(wq - 8);
    __syncthreads();
    if (wq < 4) red_add(wq);                 // w0..3 += w8..11
    __syncthreads();
    if (wq >= 12) red_write(wq - 12);
    __syncthreads();
    if (wq >= 4 && wq < 8) red_add(wq - 4);  // w4..7 += w12..15
    __syncthreads();
    if (wq >= 4 && wq < 8) red_write(wq - 4);
    __syncthreads();
    if (wq < 4) red_add(wq);                 // w0..3 += w4..7
    __syncthreads();
    if (wq >= 2 && wq < 4) red_write(wq - 2);
    __syncthreads();
    if (wq < 2) red_add(wq);                 // w0..1 += w2..3
    __syncthreads();
    if (wq == 1) red_write(0);
    __syncthreads();
    if (wq == 0) {
        red_add(0);                          // w0 = sum of all 16
        // bias + top-2 (jax tie rule: ascending scan, strict >) + softmax,
        // fully in-register (unrolled -> compile-time acc indices)
        float m1 = -INFINITY, m2 = -INFINITY;
        int i1 = 0, i2 = 0;
#pragma unroll
        for (int e = 0; e < NE; ++e) {
            const float v = acc[e] + rb[e];
            if (v > m1)      { m2 = m1; i2 = i1; m1 = v; i1 = e; }
            else if (v > m2) { m2 = v;  i2 = e; }
        }
        const float p1 = 1.f / (1.f + expf(m2 - m1));
        smem[lane]       = p1;
        smem[64 + lane]  = 1.f - p1;
        smem[128 + lane] = (float)i1;
        smem[192 + lane] = (float)i2;
    }
    __syncthreads();

    // write router_output rows (every element, zeros included), float4 coalesced
    {
        const int t  = tid >> 4;       // 0..63
        const int e0 = (tid & 15) * 4;
        const int i1 = (int)smem[128 + t];
        const int i2 = (int)smem[192 + t];
        const float p1 = smem[t];
        const float p2 = smem[64 + t];
        float v[4];
#pragma unroll
        for (int j = 0; j < 4; ++j) {
            const int e = e0 + j;
            v[j] = (e == i1) ? p1 : ((e == i2) ? p2 : 0.f);
        }
        *reinterpret_cast<float4*>(out + (tok0 + t) * NE + e0) =
            make_float4(v[0], v[1], v[2], v[3]);
    }
    if (tid < TB) {
        float* idxo = out + (long)TOKENS * NE + (tok0 + tid) * 2;
        idxo[0] = smem[128 + tid];
        idxo[1] = smem[192 + tid];
    }
}

extern "C" void kernel_launch(void* const* d_in, const int* in_sizes, int n_in,
                              void* d_out, int out_size, void* d_ws, size_t ws_size,
                              hipStream_t stream) {
    const float* x       = (const float*)d_in[0];
    const float* route_w = (const float*)d_in[2];
    const float* route_b = (const float*)d_in[3];
    float* wts = (float*)d_ws;          // 1 MB scratch
    float* out = (float*)d_out;

    hipLaunchKernelGGL(wts_prep_kernel, dim3((EMB * NE) / 256), dim3(256), 0, stream,
                       route_w, wts);
    hipLaunchKernelGGL(router_kernel, dim3(TOKENS / TB), dim3(1024), 0, stream,
                       x, wts, route_b, out);
}

// Round 11
// 255.824 us; speedup vs baseline: 1.8744x; 1.8744x over previous
//
#include <hip/hip_runtime.h>
#include <math.h>

// NoisyTopKRouter: out0 = softmax over top-2 of (x @ route_w^T + route_b) scattered
// into [16384,64]; out1 = top-2 indices (as floats). noise inputs are dead.
//
// R11: lane = token, acc[32] (R10's acc[64] spilled at the compiler's 64-VGPR
// ceiling). 16 waves/block = 2 expert-groups x 8 K-segs; block = 64 tokens,
// all 64 experts, full K -> single kernel, no merge. w via wave-uniform s_load
// (scalar path). x reg-staged (global->reg->ds_write->ds_read, wave-private
// double buffer, ALL waits compiler-managed -- no manual vmcnt, no barriers
// in the K-loop). XOR slot layout: ds_write and ds_read both conflict-free.

#define TOKENS 16384
#define EMB    4096
#define NE     64
#define TB     64                 // tokens per block (= lanes)
#define KSEG   512                // k per wave
#define NSC    (KSEG / 8)         // 64 superchunks of 8 k

// wts[kchunk][e][kk]: kchunk = k>>2, e = expert, kk = k&3  (1 MB in d_ws)
// -> per 4-k chunk, experts' float4s are contiguous (scalar-loadable slices)
__global__ __launch_bounds__(256) void wts_prep_kernel(const float* __restrict__ w,
                                                       float* __restrict__ wts) {
    int idx = blockIdx.x * 256 + threadIdx.x;   // coalesced writes
    int c  = idx >> 8;
    int e  = (idx >> 2) & 63;
    int kk = idx & 3;
    wts[idx] = w[e * EMB + c * 4 + kk];
}

__global__ __launch_bounds__(1024, 1) void router_kernel(const float* __restrict__ x,
                                                         const float* __restrict__ wts,
                                                         const float* __restrict__ rb,
                                                         float* __restrict__ out) {
    // [0..16383]: 16 waves x 4KB stage bufs; reused as 8 reduction regions
    // ([32exp][64tok] = 2048 floats each), then as lg[16][64][4] (16 KB).
    // [16384..16639]: p1/p2/i1/i2 epilogue arrays.
    __shared__ __align__(16) float smem[16384 + 256];

    const int tid  = threadIdx.x;
    const int lane = tid & 63;                                  // = token
    const int wq   = __builtin_amdgcn_readfirstlane(tid >> 6);
    const long tok0 = (long)blockIdx.x * TB;
    const int eg = wq >> 3;        // expert group: experts eg*32 .. eg*32+31
    const int ks = wq & 7;         // K-seg: k in [ks*512, ks*512+512)

    // staging: lane l stages token l>>1 (+32 for piece 1), 4-float chunk
    // c_s = (l&1)^((l>>3)&1) of each 8-k superchunk.
    const int t_s = lane >> 1;
    const int c_s = (lane & 1) ^ ((lane >> 3) & 1);
    const float* xs0 = x + (tok0 + t_s) * (long)EMB + ks * KSEG + c_s * 4;
    const float* xs1 = xs0 + 32 * (long)EMB;

    float* buf = smem + wq * 1024;     // 2 bufs x 512 floats, wave-private
    // slot layout: token t, chunk c at slot t*2 + (c^((t>>2)&1)); lane l
    // writes slot p*64+l. Both sides hit all 8 bank-quads -> conflict-free.
    const int ro0 = (lane * 2 + (((lane >> 2) & 1) ^ 0)) * 4;   // float offs
    const int ro1 = (lane * 2 + (((lane >> 2) & 1) ^ 1)) * 4;

    const float4* wts4 = (const float4*)wts;

    float acc[32];
#pragma unroll
    for (int e = 0; e < 32; ++e) acc[e] = 0.f;

    // prologue: stage superchunk 0 into buf half 0
    {
        const float4 a = *reinterpret_cast<const float4*>(xs0);
        const float4 b = *reinterpret_cast<const float4*>(xs1);
        *reinterpret_cast<float4*>(buf + lane * 4)       = a;
        *reinterpret_cast<float4*>(buf + 256 + lane * 4) = b;
    }

    for (int sc = 0; sc < NSC; ++sc) {
        const int b = sc & 1;
        const bool more = (sc + 1 < NSC);
        // issue next superchunk's global loads early (hide HBM/L2 latency)
        float4 sa, sb;
        if (more) {
            sa = *reinterpret_cast<const float4*>(xs0 + (sc + 1) * 8);
            sb = *reinterpret_cast<const float4*>(xs1 + (sc + 1) * 8);
        }
        const float* xb = buf + b * 512;
        const int kc0 = ks * 128 + sc * 2;
        {
            const float4 xv = *reinterpret_cast<const float4*>(xb + ro0);
            const float4* __restrict__ wc = wts4 + (long)kc0 * 64 + eg * 32;
#pragma unroll
            for (int e = 0; e < 32; ++e) {
                const float4 wv = wc[e];
                acc[e] = fmaf(xv.w, wv.w, fmaf(xv.z, wv.z,
                         fmaf(xv.y, wv.y, fmaf(xv.x, wv.x, acc[e]))));
            }
        }
        {
            const float4 xv = *reinterpret_cast<const float4*>(xb + ro1);
            const float4* __restrict__ wc = wts4 + (long)(kc0 + 1) * 64 + eg * 32;
#pragma unroll
            for (int e = 0; e < 32; ++e) {
                const float4 wv = wc[e];
                acc[e] = fmaf(xv.w, wv.w, fmaf(xv.z, wv.z,
                         fmaf(xv.y, wv.y, fmaf(xv.x, wv.x, acc[e]))));
            }
        }
        // write-late into the other half (wave-private; deps compiler-tracked)
        if (more) {
            float* d = buf + (b ^ 1) * 512;
            *reinterpret_cast<float4*>(d + lane * 4)       = sa;
            *reinterpret_cast<float4*>(d + 256 + lane * 4) = sb;
        }
    }

    // ---- reduction: sum 8 K-segs per expert-group (regions r at r*2048) ----
#define RED_WRITE(r)                                                           \
    {                                                                          \
        float* rb_ = smem + (r) * 2048;                                        \
        _Pragma("unroll")                                                      \
        for (int e4 = 0; e4 < 8; ++e4)                                         \
            *reinterpret_cast<float4*>(rb_ + (e4 * 64 + lane) * 4) =           \
                make_float4(acc[e4 * 4], acc[e4 * 4 + 1],                      \
                            acc[e4 * 4 + 2], acc[e4 * 4 + 3]);                 \
    }
#define RED_ADD(r)                                                             \
    {                                                                          \
        const float* rb_ = smem + (r) * 2048;                                  \
        _Pragma("unroll")                                                      \
        for (int e4 = 0; e4 < 8; ++e4) {                                       \
            const float4 v = *reinterpret_cast<const float4*>(                 \
                rb_ + (e4 * 64 + lane) * 4);                                   \
            acc[e4 * 4] += v.x; acc[e4 * 4 + 1] += v.y;                        \
            acc[e4 * 4 + 2] += v.z; acc[e4 * 4 + 3] += v.w;                    \
        }                                                                      \
    }
    __syncthreads();
    if (ks >= 4) RED_WRITE(eg * 4 + ks - 4)
    __syncthreads();
    if (ks < 4)  RED_ADD(eg * 4 + ks)
    __syncthreads();
    if (ks == 2 || ks == 3) RED_WRITE(eg * 2 + ks - 2)
    __syncthreads();
    if (ks < 2)  RED_ADD(eg * 2 + ks)
    __syncthreads();
    if (ks == 1) RED_WRITE(eg)
    __syncthreads();
    if (ks == 0) RED_ADD(eg)
    __syncthreads();   // regions 0/1 dead after this; lg overwrites them
    if (ks == 0) {     // leaders (wq 0, 8): bias + store lg[e4g][t][4]
#pragma unroll
        for (int e4 = 0; e4 < 8; ++e4) {
            const float4 bv = *reinterpret_cast<const float4*>(rb + eg * 32 + e4 * 4);
            *reinterpret_cast<float4*>(smem + ((eg * 8 + e4) * 64 + lane) * 4) =
                make_float4(acc[e4 * 4] + bv.x, acc[e4 * 4 + 1] + bv.y,
                            acc[e4 * 4 + 2] + bv.z, acc[e4 * 4 + 3] + bv.w);
        }
    }
    __syncthreads();

    // top-2 (jax tie rule: ascending scan, strict >) + 2-way softmax
    if (tid < TB) {
        const int t = tid;
        float m1 = -INFINITY, m2 = -INFINITY;
        int i1 = 0, i2 = 0;
#pragma unroll
        for (int e = 0; e < NE; ++e) {
            const float v = smem[((e >> 2) * 64 + t) * 4 + (e & 3)];
            if (v > m1)      { m2 = m1; i2 = i1; m1 = v; i1 = e; }
            else if (v > m2) { m2 = v;  i2 = e; }
        }
        const float p1 = 1.f / (1.f + expf(m2 - m1));
        smem[16384 + t]       = p1;
        smem[16384 + 64 + t]  = 1.f - p1;
        smem[16384 + 128 + t] = (float)i1;
        smem[16384 + 192 + t] = (float)i2;
    }
    __syncthreads();

    // write router_output rows (every element, zeros included), float4 coalesced
    {
        const int t  = tid >> 4;       // 0..63
        const int e0 = (tid & 15) * 4;
        const int i1 = (int)smem[16384 + 128 + t];
        const int i2 = (int)smem[16384 + 192 + t];
        const float p1 = smem[16384 + t];
        const float p2 = smem[16384 + 64 + t];
        float v[4];
#pragma unroll
        for (int j = 0; j < 4; ++j) {
            const int e = e0 + j;
            v[j] = (e == i1) ? p1 : ((e == i2) ? p2 : 0.f);
        }
        *reinterpret_cast<float4*>(out + (tok0 + t) * NE + e0) =
            make_float4(v[0], v[1], v[2], v[3]);
    }
    if (tid < TB) {
        float* idxo = out + (long)TOKENS * NE + (tok0 + tid) * 2;
        idxo[0] = smem[16384 + 128 + tid];
        idxo[1] = smem[16384 + 192 + tid];
    }
}

extern "C" void kernel_launch(void* const* d_in, const int* in_sizes, int n_in,
                              void* d_out, int out_size, void* d_ws, size_t ws_size,
                              hipStream_t stream) {
    const float* x       = (const float*)d_in[0];
    const float* route_w = (const float*)d_in[2];
    const float* route_b = (const float*)d_in[3];
    float* wts = (float*)d_ws;          // 1 MB scratch
    float* out = (float*)d_out;

    hipLaunchKernelGGL(wts_prep_kernel, dim3((EMB * NE) / 256), dim3(256), 0, stream,
                       route_w, wts);
    hipLaunchKernelGGL(router_kernel, dim3(TOKENS / TB), dim3(1024), 0, stream,
                       x, wts, route_b, out);
}

// Round 12
// 160.362 us; speedup vs baseline: 2.9902x; 1.5953x over previous
//
#include <hip/hip_runtime.h>
#include <math.h>

// NoisyTopKRouter: out0 = softmax over top-2 of (x @ route_w^T + route_b) scattered
// into [16384,64]; out1 = top-2 indices (as floats). noise inputs are dead.
//
// R12 = R7 (148.9us, proven correct) + ONE change: triple-buffered x staging
// issued 2 segments ahead. R7's residual stall: stage(s+1) issued 1-ahead gets
// drained by the compiler's own (sunk) w4a-load vmcnt waits BEFORE it lands
// (~400cy HBM exposure per 512cy segment, same phase in every wave). With a
// 2-segment lead the drain hits an already-retired load (free). gload_lds has
// no VGPR dest; sched_barrier walls bracket only it -> zero pressure delta
// (compiler ceiling is 64 VGPR: R5/R10 spilled rather than exceed it).
// vmcnt: each body issues exactly 1 stage -> younger-than-stage(s) is always
// {stage(s+1), stage(s+2)} -> uniform vmcnt(2); tail peels use 1 then 0.

#define TOKENS 16384
#define EMB    4096
#define NE     64
#define TB     32                 // tokens per block
#define NWAVES 8
#define KQ     (EMB / NWAVES)     // 512 k per wave (split-K)
#define KR     8                  // k per segment (= per stage)
#define NSEG   (KQ / KR)          // 64

#define GLOAD_LDS16(g, l)                                                      \
    __builtin_amdgcn_global_load_lds(                                          \
        (const __attribute__((address_space(1))) void*)(g),                    \
        (__attribute__((address_space(3))) void*)(l), 16, 0, 0)

// wt4[k][le][m] = route_w[le + 16*m][k]  (1 MB in d_ws; lane le reads its 4
// experts {le, le+16, le+32, le+48} for one k as a single float4)
__global__ __launch_bounds__(256) void wt4_prep_kernel(const float* __restrict__ w,
                                                       float* __restrict__ wt4) {
    int idx = blockIdx.x * 256 + threadIdx.x;
    int k   = idx >> 6;
    int col = idx & 63;
    int le  = col >> 2;
    int m   = col & 3;
    wt4[idx] = w[(le + 16 * m) * EMB + k];
}

__global__ __launch_bounds__(512, 4) void router_kernel(const float* __restrict__ x,
                                                        const float* __restrict__ wt4,
                                                        const float* __restrict__ rb,
                                                        float* __restrict__ out) {
    // 32 KB: xstage = 8 waves x 3 bufs x 256 floats (first 24 KB);
    // after the K-loop the whole region is reused as red[4][32][64] (32 KB).
    __shared__ float smem[8192];

    const int tid  = threadIdx.x;
    const int lane = tid & 63;
    const int wq   = __builtin_amdgcn_readfirstlane(tid >> 6);
    const long tok0 = (long)blockIdx.x * TB;

    const int g  = lane >> 4;      // token group: tokens g*8..g*8+7
    const int le = lane & 15;      // expert lane: experts le + 16*m
    const int swz   = g << 4;      // byte XOR for swizzled x reads (bits 4..5)
    const int tbase = g * 256;     // token-group byte base (bits 8..9)

    // staging source (inverse of the read-side XOR swizzle; verified R3/R4/R7):
    // linear buf layout: token t bytes [t*32, t*32+32), half h at +h*16;
    // read addr = (t*32 + h*16) ^ ((t>>3)<<4).
    const int r_  = lane >> 1;
    const int hl  = lane & 1;
    const int t_s = r_ ^ ((r_ >> 4) & 1);
    const int h_s = hl ^ ((r_ >> 3) & 1);
    const float* xsrc = x + (tok0 + t_s) * (long)EMB + wq * KQ + 4 * h_s;

    const float* wsrc = wt4 + (long)(wq * KQ) * NE + le * 4;

    float acc[8][4];
#pragma unroll
    for (int i = 0; i < 8; ++i)
#pragma unroll
        for (int m = 0; m < 4; ++m) acc[i][m] = 0.f;

    float* bufB = &smem[wq * 768];   // 3 bufs x 256 floats, wave-private

    auto compute_seg = [&](const float* __restrict__ wseg,
                           const char* __restrict__ xb) {
        float w4a[KR][4];
#pragma unroll
        for (int k = 0; k < KR; ++k)
            *reinterpret_cast<float4*>(&w4a[k][0]) =
                *reinterpret_cast<const float4*>(wseg + k * NE);
#pragma unroll
        for (int i = 0; i < 8; ++i) {
            const float4 xa = *reinterpret_cast<const float4*>(xb + ((tbase + i * 32 + 0)  ^ swz));
            const float4 xc = *reinterpret_cast<const float4*>(xb + ((tbase + i * 32 + 16) ^ swz));
#pragma unroll
            for (int m = 0; m < 4; ++m) {
                float a = acc[i][m];
                a = fmaf(xa.x, w4a[0][m], a);
                a = fmaf(xa.y, w4a[1][m], a);
                a = fmaf(xa.z, w4a[2][m], a);
                a = fmaf(xa.w, w4a[3][m], a);
                a = fmaf(xc.x, w4a[4][m], a);
                a = fmaf(xc.y, w4a[5][m], a);
                a = fmaf(xc.z, w4a[6][m], a);
                a = fmaf(xc.w, w4a[7][m], a);
                acc[i][m] = a;
            }
        }
    };

    // prologue: stage segments 0 and 1 into bufs 0 and 1
    GLOAD_LDS16(xsrc + 0 * KR, bufB + 0 * 256);
    GLOAD_LDS16(xsrc + 1 * KR, bufB + 1 * 256);

    // body: stage(s+2) 2-ahead into buf[(s+2)%3]; vmcnt(2) -> stage(s) done
    // (and long-retired: it was issued ~1000cy earlier). Walls pin only the
    // destless gload_lds -> no register-pressure delta vs R7.
#define SEG_BODY(S, M, VM)                                                     \
    {                                                                          \
        if ((VM) == 2) {                                                       \
            __builtin_amdgcn_sched_barrier(0);                                 \
            GLOAD_LDS16(xsrc + ((S) + 2) * KR, bufB + (((M) + 2) % 3) * 256);  \
            __builtin_amdgcn_sched_barrier(0);                                 \
        }                                                                      \
        asm volatile("s_waitcnt vmcnt(" #VM ")" ::: "memory");                 \
        compute_seg(wsrc + (long)(S) * KR * NE,                                \
                    (const char*)(bufB + (M) * 256));                          \
    }

    for (int s = 0; s < NSEG - 4; s += 3) {      // s = 0,3,...,57
        SEG_BODY(s + 0, 0, 2)
        SEG_BODY(s + 1, 1, 2)
        SEG_BODY(s + 2, 2, 2)
    }
    SEG_BODY(NSEG - 4, 0, 2)     // s=60, stages 62 -> buf 2
    SEG_BODY(NSEG - 3, 1, 2)     // s=61, stages 63 -> buf 0
    SEG_BODY(NSEG - 2, 2, 1)     // s=62, no stage; stage(63) still outstanding
    SEG_BODY(NSEG - 1, 0, 0)     // s=63
#undef SEG_BODY

    // ---- two-round cross-wave reduction (aliases xstage; barrier-separated) ----
    __syncthreads();
    if (wq >= 4) {   // round A: waves 4..7 store partials
#pragma unroll
        for (int i = 0; i < 8; ++i)
#pragma unroll
            for (int m = 0; m < 4; ++m)
                smem[((wq & 3) * 32 + g * 8 + i) * 64 + le + 16 * m] = acc[i][m];
    }
    __syncthreads();
    if (wq < 4) {    // round B: waves 0..3 accumulate into the same cells
#pragma unroll
        for (int i = 0; i < 8; ++i)
#pragma unroll
            for (int m = 0; m < 4; ++m) {
                const int idx = ((wq & 3) * 32 + g * 8 + i) * 64 + le + 16 * m;
                smem[idx] += acc[i][m];
            }
    }
    __syncthreads();
    // final 4-way sum + bias -> smem[t*64+e] (each (t,e) owned by one thread)
    {
        const int t  = tid >> 4;          // 0..31
        const int e0 = (tid & 15) * 4;
        float4 sum = *reinterpret_cast<const float4*>(rb + e0);
#pragma unroll
        for (int r = 0; r < 4; ++r) {
            const float4 p = *reinterpret_cast<const float4*>(&smem[(r * 32 + t) * 64 + e0]);
            sum.x += p.x; sum.y += p.y; sum.z += p.z; sum.w += p.w;
        }
        *reinterpret_cast<float4*>(&smem[t * 64 + e0]) = sum;
    }
    __syncthreads();

    // top-2 (jax tie rule: ascending scan, strict >) + 2-way softmax
    if (tid < TB) {
        const int t = tid;
        float m1 = -INFINITY, m2 = -INFINITY;
        int i1 = 0, i2 = 0;
        for (int e = 0; e < NE; ++e) {
            float v = smem[t * 64 + e];
            if (v > m1)      { m2 = m1; i2 = i1; m1 = v; i1 = e; }
            else if (v > m2) { m2 = v;  i2 = e; }
        }
        const float ed = expf(m2 - m1);
        const float p1 = 1.f / (1.f + ed);
        smem[2048 + t]      = p1;
        smem[2048 + 32 + t] = 1.f - p1;
        smem[2048 + 64 + t] = (float)i1;
        smem[2048 + 96 + t] = (float)i2;
    }
    __syncthreads();

    // write router_output rows (every element, zeros included), float4 coalesced
    {
        const int t  = tid >> 4;
        const int e0 = (tid & 15) * 4;
        const int i1 = (int)smem[2048 + 64 + t];
        const int i2 = (int)smem[2048 + 96 + t];
        const float p1 = smem[2048 + t];
        const float p2 = smem[2048 + 32 + t];
        float v[4];
#pragma unroll
        for (int j = 0; j < 4; ++j) {
            const int e = e0 + j;
            v[j] = (e == i1) ? p1 : ((e == i2) ? p2 : 0.f);
        }
        *reinterpret_cast<float4*>(out + (tok0 + t) * NE + e0) =
            make_float4(v[0], v[1], v[2], v[3]);
    }
    if (tid < TB) {
        float* idxo = out + (long)TOKENS * NE + (tok0 + tid) * 2;
        idxo[0] = smem[2048 + 64 + tid];
        idxo[1] = smem[2048 + 96 + tid];
    }
}

extern "C" void kernel_launch(void* const* d_in, const int* in_sizes, int n_in,
                              void* d_out, int out_size, void* d_ws, size_t ws_size,
                              hipStream_t stream) {
    const float* x       = (const float*)d_in[0];
    const float* route_w = (const float*)d_in[2];
    const float* route_b = (const float*)d_in[3];
    float* wt4 = (float*)d_ws;          // 1 MB scratch
    float* out = (float*)d_out;

    hipLaunchKernelGGL(wt4_prep_kernel, dim3((EMB * NE) / 256), dim3(256), 0, stream,
                       route_w, wt4);
    hipLaunchKernelGGL(router_kernel, dim3(TOKENS / TB), dim3(512), 0, stream,
                       x, wt4, route_b, out);
}